// Round 5
// baseline (6561.548 us; speedup 1.0000x reference)
//
#include <hip/hip_runtime.h>
#include <hip/hip_bf16.h>

#define BATCH 2048
#define SEQ   80
#define EMBD  100
#define HU    512
#define NG    2048
#define NBLK  256

typedef short bf16x8 __attribute__((ext_vector_type(8)));
typedef float f32x4  __attribute__((ext_vector_type(4)));
typedef int   i32x4  __attribute__((ext_vector_type(4)));

#define AS1(p) ((const __attribute__((address_space(1))) void*)(p))
#define AS3(p) ((__attribute__((address_space(3))) void*)(p))

// ---------------- prep kernels ----------------
__global__ __launch_bounds__(256) void prep_emb(const float* __restrict__ emb,
                                                __hip_bfloat16* __restrict__ embp)
{
    int idx = blockIdx.x*256 + threadIdx.x;
    int row = idx >> 7, k = idx & 127;
    embp[idx] = __float2bfloat16(k < EMBD ? emb[row*EMBD + k] : 0.f);
}

// Gate-interleaved transposed weights. n = u*4 + g, col_orig = g*512 + u.
__global__ __launch_bounds__(256) void prep_wt(
    const float* __restrict__ W1, const float* __restrict__ U1, const float* __restrict__ b1,
    const float* __restrict__ W2, const float* __restrict__ U2, const float* __restrict__ b2,
    __hip_bfloat16* __restrict__ wt1, __hip_bfloat16* __restrict__ wt2,
    float* __restrict__ bp1, float* __restrict__ bp2)
{
    const int n = blockIdx.x;
    const int u = n >> 2, g = n & 3, col = g*HU + u;
    if (blockIdx.y == 0) {
        for (int k = threadIdx.x; k < 640; k += 256) {
            float v = (k < EMBD) ? W1[k*NG + col] : ((k < 128) ? 0.f : U1[(k-128)*NG + col]);
            wt1[n*640 + k] = __float2bfloat16(v);
        }
        if (threadIdx.x == 0) bp1[n] = b1[col];
    } else {
        for (int k = threadIdx.x; k < 1024; k += 256) {
            float v = (k < HU) ? W2[k*NG + col] : U2[(k-HU)*NG + col];
            wt2[n*1024 + k] = __float2bfloat16(v);
        }
        if (threadIdx.x == 0) bp2[n] = b2[col];
    }
}

// ---------------- persistent LSTM ----------------
// 256 blocks (8 uB x 32 rB), 512 threads, block tile = 64 batch-rows x 256 gate-cols.
// h coherence via volatile (sc0 sc1) loads/stores; weights stay L2-resident (no fences).
__global__ __launch_bounds__(512, 2) void lstm_persist(
    const int* __restrict__ ids,
    const __hip_bfloat16* __restrict__ embp,
    const __hip_bfloat16* __restrict__ wt1, const float* __restrict__ bp1,
    const __hip_bfloat16* __restrict__ wt2, const float* __restrict__ bp2,
    __hip_bfloat16* __restrict__ h1a, __hip_bfloat16* __restrict__ h1b,
    __hip_bfloat16* __restrict__ h2a, __hip_bfloat16* __restrict__ h2b,
    unsigned long long* bar)
{
    __shared__ __align__(16) unsigned short hx[64*520];   // h1[r-1] rows, pad-stride 520 (66.5KB)
    __shared__ __align__(16) unsigned short Bs[2][16384]; // weight dbuf (64KB)
    __shared__ __align__(16) unsigned short sb[2][4096];  // stream dbuf embp/h2 + h-out stage (16KB)

    const int tid = threadIdx.x;
    const int w = tid >> 6, lane = tid & 63;
    const int l15 = lane & 15, tq = lane >> 4;
    const int wM = w >> 2, wN = w & 3;            // wave tile: rows wM*32+, cols wN*64+
    const int uB = blockIdx.x & 7, rB = blockIdx.x >> 3;
    const int m0 = rB * 64, n0 = uB * 256;

    float c1r[4][2][4] = {};                      // cell state, live on gq==1 lanes
    float c2r[4][2][4] = {};
    f32x4 acc[2][4];

    auto zacc = [&](){
        #pragma unroll
        for (int mi = 0; mi < 2; ++mi)
            #pragma unroll
            for (int ni = 0; ni < 4; ++ni)
                acc[mi][ni] = (f32x4){0.f,0.f,0.f,0.f};
    };

    auto stageB = [&](const __hip_bfloat16* wt, int KTOT, int kt, unsigned short* Bd){
        const int k0 = kt * 64;
        #pragma unroll
        for (int cc = 0; cc < 2; ++cc) {
            const int chunk = w*2 + cc;
            #pragma unroll
            for (int j = 0; j < 2; ++j) {
                const __hip_bfloat16* gp = wt + (size_t)(n0 + chunk*16 + l15)*KTOT
                                              + k0 + (j*4 + tq)*8;
                __builtin_amdgcn_global_load_lds(AS1(gp), AS3(Bd + chunk*1024 + j*512), 16, 0, 0);
            }
        }
    };

    auto afragS = [&](const unsigned short* S, int s, int mi) -> bf16x8 {
        return *(const bf16x8*)&S[(wM*2 + mi)*1024 + (s*4 + tq)*128 + l15*8];
    };
    auto afragH = [&](int kb, int s, int mi) -> bf16x8 {
        const int row = wM*32 + mi*16 + l15;
        const int kp  = kb + s*32 + tq*8;
        return *(const bf16x8*)((const char*)hx + row*1040 + kp*2);
    };
    auto mma2 = [&](bf16x8 a0, bf16x8 a1, const unsigned short* Bb, int s){
        bf16x8 bF[4];
        #pragma unroll
        for (int ni = 0; ni < 4; ++ni)
            bF[ni] = *(const bf16x8*)&Bb[(wN*4 + ni)*1024 + (s*4 + tq)*128 + l15*8];
        #pragma unroll
        for (int ni = 0; ni < 4; ++ni) {
            acc[0][ni] = __builtin_amdgcn_mfma_f32_16x16x32_bf16(a0, bF[ni], acc[0][ni], 0, 0, 0);
            acc[1][ni] = __builtin_amdgcn_mfma_f32_16x16x32_bf16(a1, bF[ni], acc[1][ni], 0, 0, 0);
        }
    };

    auto sbwrite = [&](unsigned short* S, i32x4 v){
        const int row = tid >> 3, t8 = tid & 7;
        *(i32x4*)((char*)S + ((row >> 4)*1024 + t8*128 + (row & 15)*8)*2) = v;
    };
    auto hxwrite = [&](i32x4* hr){
        #pragma unroll
        for (int t = 0; t < 8; ++t)
            *(i32x4*)((char*)hx + (t*8 + (tid >> 6))*1040 + (tid & 63)*16) = hr[t];
    };

    // epilogue: gates (4-lane group = i,f,g,o of one unit), c in regs, h via LDS + coherent store
    auto epilogue = [&](const float* bp, float (&cr)[4][2][4], __hip_bfloat16* hdst){
        const int gq = lane & 3;
        const bool isT = (gq == 2);
        unsigned short* hs = &sb[0][0];           // viewed as [64][72] (9216B < 16KB)
        #pragma unroll
        for (int ni = 0; ni < 4; ++ni) {
            const int nl = wN*64 + ni*16 + l15;
            const float bv = bp[n0 + nl];
            const int ul = nl >> 2;
            #pragma unroll
            for (int mi = 0; mi < 2; ++mi) {
                #pragma unroll
                for (int rr = 0; rr < 4; ++rr) {
                    const int rowl = wM*32 + mi*16 + tq*4 + rr;
                    const float z  = acc[mi][ni][rr] + bv;
                    const float zz = isT ? 2.f*z : z;
                    const float sg = 1.f/(1.f + __expf(-zz));
                    const float act = isT ? fmaf(2.f, sg, -1.f) : sg;   // tanh via sigmoid
                    const float act2 = __shfl_xor(act, 2);    // i<->g, f<->o
                    const float pig  = act * act2;            // gq0: sig(i)*tanh(g)
                    const float pig1 = __shfl_xor(pig, 1);    // gq1 <- gq0
                    const float cn  = fmaf(act, cr[ni][mi][rr], pig1);  // gq1: sig(f)*c + i*g
                    const float tcn = fmaf(2.f, 1.f/(1.f + __expf(-2.f*cn)), -1.f);
                    const float tcn2 = __shfl_xor(tcn, 2);    // gq3 <- gq1
                    const float hv  = act * tcn2;             // gq3: sig(o)*tanh(c)
                    if (gq == 1) cr[ni][mi][rr] = cn;
                    if (gq == 3) {
                        __hip_bfloat16 hb = __float2bfloat16(hv);
                        hs[rowl*72 + ul] = *(unsigned short*)&hb;
                    }
                }
            }
        }
        __syncthreads();
        const int row = tid >> 3, ch = tid & 7;
        i32x4 v = *(const i32x4*)((const char*)hs + row*144 + ch*16);
        *(volatile i32x4*)(hdst + (size_t)(m0 + row)*HU + uB*64 + ch*8) = v;   // sc0 sc1
        __syncthreads();
    };

    // fence-free grid barrier: u64 {gen:32, cnt:32}, all RELAXED (no buffer_inv/wbl2)
    auto gbar = [&](){
        asm volatile("s_waitcnt vmcnt(0)" ::: "memory");   // coherent stores globally visible
        __syncthreads();
        if (tid == 0) {
            unsigned long long old = __hip_atomic_fetch_add(bar, 1ull,
                                        __ATOMIC_RELAXED, __HIP_MEMORY_SCOPE_AGENT);
            unsigned g = (unsigned)(old >> 32);
            if ((unsigned)(old & 0xffffffffull) == NBLK - 1u) {
                __hip_atomic_fetch_add(bar, (1ull << 32) - (unsigned long long)NBLK,
                                       __ATOMIC_RELAXED, __HIP_MEMORY_SCOPE_AGENT);
            } else {
                while ((unsigned)(__hip_atomic_load(bar, __ATOMIC_RELAXED,
                                        __HIP_MEMORY_SCOPE_AGENT) >> 32) == g)
                    __builtin_amdgcn_s_sleep(8);
            }
        }
        __syncthreads();
        asm volatile("" ::: "memory");
    };

    for (int r = 0; r <= SEQ; ++r) {
        const int ip = (r - 1) & 1, ic = r & 1;
        const __hip_bfloat16* h1p = ip ? h1b : h1a;   // h1_out[r-1]
        __hip_bfloat16*       h1c = ic ? h1b : h1a;   // h1_out[r]
        const __hip_bfloat16* h2c = ic ? h2b : h2a;   // h2_out[r-2]
        __hip_bfloat16*       h2p = ip ? h2b : h2a;   // h2_out[r-1]

        // coherent h loads for this round (deep prefetch into regs)
        i32x4 hreg[8];
        #pragma unroll
        for (int t = 0; t < 8; ++t)
            hreg[t] = *(const volatile i32x4*)(h1p + (size_t)(m0 + t*8 + (tid >> 6))*HU
                                                   + (tid & 63)*8);
        i32x4 h2g[8];
        if (r >= 1) {
            #pragma unroll
            for (int j = 0; j < 8; ++j)
                h2g[j] = *(const volatile i32x4*)(h2c + (size_t)(m0 + (tid >> 3))*HU
                                                      + j*64 + (tid & 7)*8);
        }

        if (r < SEQ) {
            // ---------------- Layer 1: t = r, K = 640 (embp 0..127 | h1p 128..639) ----------
            const int myid = ids[(m0 + (tid >> 3))*SEQ + r];
            const __hip_bfloat16* erow = embp + (size_t)myid*128 + (tid & 7)*8;
            i32x4 e0 = *(const i32x4*)(erow);
            i32x4 e1 = *(const i32x4*)(erow + 64);
            zacc();
            stageB(wt1, 640, 0, &Bs[0][0]);
            sbwrite(&sb[0][0], e0);
            __syncthreads();
            // kt0 (A = embp via sb0)
            stageB(wt1, 640, 1, &Bs[1][0]);
            sbwrite(&sb[1][0], e1);
            #pragma unroll
            for (int s = 0; s < 2; ++s)
                mma2(afragS(&sb[0][0], s, 0), afragS(&sb[0][0], s, 1), &Bs[0][0], s);
            __syncthreads();
            // kt1 (A = embp via sb1); write hx for kt2+
            stageB(wt1, 640, 2, &Bs[0][0]);
            hxwrite(hreg);
            #pragma unroll
            for (int s = 0; s < 2; ++s)
                mma2(afragS(&sb[1][0], s, 0), afragS(&sb[1][0], s, 1), &Bs[1][0], s);
            __syncthreads();
            // kt2..9 (A = hx)
            #pragma unroll
            for (int kt = 2; kt < 10; ++kt) {
                if (kt < 9) stageB(wt1, 640, kt + 1, &Bs[(kt + 1) & 1][0]);
                const int kb = (kt - 2)*64;
                #pragma unroll
                for (int s = 0; s < 2; ++s)
                    mma2(afragH(kb, s, 0), afragH(kb, s, 1), &Bs[kt & 1][0], s);
                __syncthreads();
            }
            epilogue(bp1, c1r, h1c);
        } else {
            hxwrite(hreg);
            __syncthreads();
        }

        if (r >= 1) {
            // ---------------- Layer 2: t = r-1, K = 1024 (h1p 0..511 | h2c 512..1023) -------
            zacc();
            stageB(wt2, 1024, 0, &Bs[0][0]);
            __syncthreads();
            #pragma unroll
            for (int kt = 0; kt < 16; ++kt) {
                if (kt < 15) stageB(wt2, 1024, kt + 1, &Bs[(kt + 1) & 1][0]);
                if (kt >= 7 && kt < 15) sbwrite(&sb[(kt + 1) & 1][0], h2g[kt - 7]);
                if (kt < 8) {
                    const int kb = kt*64;
                    #pragma unroll
                    for (int s = 0; s < 2; ++s)
                        mma2(afragH(kb, s, 0), afragH(kb, s, 1), &Bs[kt & 1][0], s);
                } else {
                    #pragma unroll
                    for (int s = 0; s < 2; ++s)
                        mma2(afragS(&sb[kt & 1][0], s, 0), afragS(&sb[kt & 1][0], s, 1),
                             &Bs[kt & 1][0], s);
                }
                __syncthreads();
            }
            epilogue(bp2, c2r, h2p);
        }
        gbar();
    }
}

// out[b] = sigmoid(h2[b,:] @ Wd + bd)
__global__ __launch_bounds__(256) void head_k(const __hip_bfloat16* __restrict__ h2,
    const float* __restrict__ Wd, const float* __restrict__ bd, float* __restrict__ out)
{
    const int b = blockIdx.x*4 + (threadIdx.x >> 6);
    const int lane = threadIdx.x & 63;
    float s = 0.f;
    #pragma unroll
    for (int u = lane; u < HU; u += 64) s += __bfloat162float(h2[b*HU + u]) * Wd[u];
    #pragma unroll
    for (int off = 32; off > 0; off >>= 1) s += __shfl_xor(s, off);
    if (lane == 0) out[b] = 1.f/(1.f + __expf(-(s + bd[0])));
}

extern "C" void kernel_launch(void* const* d_in, const int* in_sizes, int n_in,
                              void* d_out, int out_size, void* d_ws, size_t ws_size,
                              hipStream_t stream)
{
    const int*   ids = (const int*)  d_in[0];
    const float* emb = (const float*)d_in[1];
    const float* W1  = (const float*)d_in[2];
    const float* U1  = (const float*)d_in[3];
    const float* b1  = (const float*)d_in[4];
    const float* W2  = (const float*)d_in[5];
    const float* U2  = (const float*)d_in[6];
    const float* b2  = (const float*)d_in[7];
    const float* Wd  = (const float*)d_in[8];
    const float* bd  = (const float*)d_in[9];
    float* out = (float*)d_out;

    const size_t HS = (size_t)BATCH*HU;
    char* p = (char*)d_ws;
    unsigned long long* bar = (unsigned long long*)p;  p += 256;
    __hip_bfloat16* h1a = (__hip_bfloat16*)p;          p += HS*2;
    __hip_bfloat16* h1b = (__hip_bfloat16*)p;          p += HS*2;
    __hip_bfloat16* h2a = (__hip_bfloat16*)p;          p += HS*2;
    __hip_bfloat16* h2b = (__hip_bfloat16*)p;          p += HS*2;
    __hip_bfloat16* embp = (__hip_bfloat16*)p;         p += (size_t)10000*128*2;
    __hip_bfloat16* wt1  = (__hip_bfloat16*)p;         p += (size_t)2048*640*2;
    __hip_bfloat16* wt2  = (__hip_bfloat16*)p;         p += (size_t)2048*1024*2;
    float* bp1 = (float*)p;                            p += 2048*4;
    float* bp2 = (float*)p;                            p += 2048*4;

    // zero barrier + h buffers each call (deterministic under graph replay)
    hipMemsetAsync(d_ws, 0, 256 + 4*HS*2, stream);

    prep_emb<<<10000*128/256, 256, 0, stream>>>(emb, embp);
    prep_wt<<<dim3(2048,2), 256, 0, stream>>>(W1,U1,b1,W2,U2,b2, wt1,wt2,bp1,bp2);

    lstm_persist<<<NBLK, 512, 0, stream>>>(ids, embp, wt1, bp1, wt2, bp2,
                                           h1a, h1b, h2a, h2b, bar);

    // round 80 wrote h2_out[79] into h2[(80-1)&1] = h2b
    head_k<<<BATCH/4, 256, 0, stream>>>(h2b, Wd, bd, out);
}